// Round 14
// baseline (364.440 us; speedup 1.0000x reference)
//
#include <hip/hip_runtime.h>
#include <hip/hip_bf16.h>
#include <hip/hip_fp8.h>

#define ROWS 8192      // B*S
#define K2   2048      // 2*DIM
#define NCPT 2048
#define DIMD 1024

using short8 = __attribute__((ext_vector_type(8))) short;
using f32x4  = __attribute__((ext_vector_type(4))) float;
using int8v  = __attribute__((ext_vector_type(8))) int;

__device__ __forceinline__ unsigned short f2b(float f) {
  __hip_bfloat16 h = __float2bfloat16(f);
  return *reinterpret_cast<unsigned short*>(&h);
}
__device__ __forceinline__ float b2f(unsigned short u) {
  unsigned int x = ((unsigned int)u) << 16;
  return __uint_as_float(x);
}
__device__ __forceinline__ unsigned char f2f8(float f) {
  __hip_fp8_e4m3 h(f);
  return (unsigned char)h.__x;
}

__device__ __forceinline__ void store_bf16x8(unsigned short* dst, const float4& a, const float4& b) {
  union { unsigned short u[8]; uint4 q; } p;
  p.u[0]=f2b(a.x); p.u[1]=f2b(a.y); p.u[2]=f2b(a.z); p.u[3]=f2b(a.w);
  p.u[4]=f2b(b.x); p.u[5]=f2b(b.y); p.u[6]=f2b(b.z); p.u[7]=f2b(b.w);
  *reinterpret_cast<uint4*>(dst) = p.q;
}
__device__ __forceinline__ void store_bf16x4(unsigned short* dst, float a, float b, float c, float d) {
  union { unsigned short u[4]; uint2 q; } p;
  p.u[0]=f2b(a); p.u[1]=f2b(b); p.u[2]=f2b(c); p.u[3]=f2b(d);
  *reinterpret_cast<uint2*>(dst) = p.q;
}
__device__ __forceinline__ void store_fp8x8(unsigned char* dst, const float4& a, const float4& b, float s) {
  union { unsigned char c[8]; uint2 q; } p;
  p.c[0]=f2f8(a.x*s); p.c[1]=f2f8(a.y*s); p.c[2]=f2f8(a.z*s); p.c[3]=f2f8(a.w*s);
  p.c[4]=f2f8(b.x*s); p.c[5]=f2f8(b.y*s); p.c[6]=f2f8(b.z*s); p.c[7]=f2f8(b.w*s);
  *reinterpret_cast<uint2*>(dst) = p.q;
}

__device__ __forceinline__ void async_lds16(const void* g, void* l) {
  __builtin_amdgcn_global_load_lds((__attribute__((address_space(1))) void*)g,
                                   (__attribute__((address_space(3))) void*)l, 16, 0, 0);
}

// ---------------- cast (bf16 optional + fp8 scaled) + row magnitude ----------------
__global__ void cast_row_mag(const float* __restrict__ src, unsigned short* __restrict__ dst_bf,
                             unsigned char* __restrict__ dst_f8, float fscale,
                             float* __restrict__ mag, int ncol) {
  __shared__ float sred[4];
  int row = blockIdx.x, t = threadIdx.x;
  const float* s = src + (size_t)row * ncol;
  float ss = 0.f;
  for (int i = t * 8; i < ncol; i += 2048) {
    float4 a = *(const float4*)(s + i);
    float4 b = *(const float4*)(s + i + 4);
    ss += a.x*a.x + a.y*a.y + a.z*a.z + a.w*a.w;
    ss += b.x*b.x + b.y*b.y + b.z*b.z + b.w*b.w;
    if (dst_bf) store_bf16x8(dst_bf + (size_t)row * ncol + i, a, b);
    store_fp8x8(dst_f8 + (size_t)row * ncol + i, a, b, fscale);
  }
  int lane = t & 63, w = t >> 6;
  for (int o = 32; o; o >>= 1) ss += __shfl_down(ss, o);
  if (lane == 0) sred[w] = ss;
  __syncthreads();
  if (t == 0) mag[row] = sqrtf(sred[0] + sred[1] + sred[2] + sred[3] + 1e-8f);
}

// ---------------- fused fp32 -> bf16 cast for Wl (2M) + Wo (1M) ----------------
__global__ void cast_w(const float* __restrict__ wl, const float* __restrict__ wo,
                       unsigned short* __restrict__ dst) {
  int b = blockIdx.x;
  const float* src;
  unsigned short* d;
  if (b < 1024) { src = wl + (size_t)b * 2048; d = dst + (size_t)b * 2048; }
  else {
    src = wo + (size_t)(b - 1024) * 2048;
    d = dst + (size_t)2 * 1024 * 1024 + (size_t)(b - 1024) * 2048;
  }
  int i = threadIdx.x * 8;
  float4 a = *(const float4*)(src + i);
  float4 c = *(const float4*)(src + i + 4);
  store_bf16x8(d + i, a, c);
}

// ---------------- transpose fp32 [n][n] -> fp8 (x16) [n][n]^T ----------------
__global__ void transpose_f8(const float* __restrict__ src, unsigned char* __restrict__ dst, int n) {
  __shared__ float tile[32][33];
  int bx = blockIdx.x * 32;
  int by = blockIdx.y * 32;
  int tx = threadIdx.x & 31, ty = threadIdx.x >> 5;
  #pragma unroll
  for (int i = ty; i < 32; i += 8)
    tile[i][tx] = src[(size_t)(by + i) * n + bx + tx];
  __syncthreads();
  #pragma unroll
  for (int i = ty; i < 32; i += 8)
    dst[(size_t)(bx + i) * n + by + tx] = f2f8(16.f * tile[tx][i]);
}

// ---------------- softmax over concepts (bf16 logits in, fp8 x256 attn out) ----------------
__global__ void softmax_attn(const unsigned short* __restrict__ logit, unsigned char* __restrict__ attn) {
  __shared__ float sred[4];
  int row = blockIdx.x, t = threadIdx.x;
  int lane = t & 63, w = t >> 6;
  const unsigned short* lr = logit + (size_t)row * NCPT + t * 8;
  short8 lv = *reinterpret_cast<const short8*>(lr);
  float l[8];
  #pragma unroll
  for (int i = 0; i < 8; ++i) l[i] = b2f((unsigned short)lv[i]);
  float m = l[0];
  #pragma unroll
  for (int i = 1; i < 8; ++i) m = fmaxf(m, l[i]);
  for (int o = 32; o; o >>= 1) m = fmaxf(m, __shfl_down(m, o));
  if (lane == 0) sred[w] = m;
  __syncthreads();
  m = fmaxf(fmaxf(sred[0], sred[1]), fmaxf(sred[2], sred[3]));
  __syncthreads();
  float e[8], s = 0.f;
  #pragma unroll
  for (int i = 0; i < 8; ++i) { e[i] = expf(l[i] - m); s += e[i]; }
  for (int o = 32; o; o >>= 1) s += __shfl_down(s, o);
  if (lane == 0) sred[w] = s;
  __syncthreads();
  s = sred[0] + sred[1] + sred[2] + sred[3];
  float inv = 256.f / s;   // x256 folded into the normalization
  float4 A = make_float4(e[0]*inv, e[1]*inv, e[2]*inv, e[3]*inv);
  float4 B = make_float4(e[4]*inv, e[5]*inv, e[6]*inv, e[7]*inv);
  store_fp8x8(attn + (size_t)row * NCPT + t * 8, A, B, 1.f);
}

// ---------------- per-component LayerNorm (bf16 h in); de-interleaves to bf16 rows ----------------
__global__ void phase_ln(const unsigned short* __restrict__ h, const float* __restrict__ gamma,
                         const float* __restrict__ beta, unsigned short* __restrict__ out) {
  __shared__ float4 s4[4];
  int bs = blockIdx.x, t = threadIdx.x;
  const unsigned short* hr = h + (size_t)bs * 2048 + t * 8;
  short8 hv = *reinterpret_cast<const short8*>(hr);
  float r0 = b2f((unsigned short)hv[0]), i0 = b2f((unsigned short)hv[1]);
  float r1 = b2f((unsigned short)hv[2]), i1 = b2f((unsigned short)hv[3]);
  float r2 = b2f((unsigned short)hv[4]), i2 = b2f((unsigned short)hv[5]);
  float r3 = b2f((unsigned short)hv[6]), i3 = b2f((unsigned short)hv[7]);
  float4 s;
  s.x = r0 + r1 + r2 + r3;
  s.y = r0*r0 + r1*r1 + r2*r2 + r3*r3;
  s.z = i0 + i1 + i2 + i3;
  s.w = i0*i0 + i1*i1 + i2*i2 + i3*i3;
  int lane = t & 63, w = t >> 6;
  for (int o = 32; o; o >>= 1) {
    s.x += __shfl_down(s.x, o); s.y += __shfl_down(s.y, o);
    s.z += __shfl_down(s.z, o); s.w += __shfl_down(s.w, o);
  }
  if (lane == 0) s4[w] = s;
  __syncthreads();
  float4 T = s4[0];
  #pragma unroll
  for (int i = 1; i < 4; ++i) { T.x += s4[i].x; T.y += s4[i].y; T.z += s4[i].z; T.w += s4[i].w; }
  const float invd = 1.f / 1024.f;
  float mu_r = T.x * invd, var_r = T.y * invd - mu_r * mu_r;
  float mu_i = T.z * invd, var_i = T.w * invd - mu_i * mu_i;
  float is_r = 1.f / sqrtf(var_r + 1e-5f);
  float is_i = 1.f / sqrtf(var_i + 1e-5f);
  float4 g = *(const float4*)(gamma + t * 4);
  float4 b = *(const float4*)(beta + t * 4);
  unsigned short* o0 = out + (size_t)(2 * bs) * 1024 + t * 4;
  unsigned short* o1 = out + (size_t)(2 * bs + 1) * 1024 + t * 4;
  store_bf16x4(o0, (r0-mu_r)*is_r*g.x + b.x, (r1-mu_r)*is_r*g.y + b.y,
                   (r2-mu_r)*is_r*g.z + b.z, (r3-mu_r)*is_r*g.w + b.w);
  store_bf16x4(o1, (i0-mu_i)*is_i*g.x + b.x, (i1-mu_i)*is_i*g.y + b.y,
                   (i2-mu_i)*is_i*g.z + b.z, (i3-mu_i)*is_i*g.w + b.w);
}

// =====================================================================
// bf16 GEMM (r5 core, unchanged): used for EPI 2 (FFN) and 3 (out).
// =====================================================================
template <int EPI>
__global__ __launch_bounds__(512, 2) void gemm256(
    const unsigned short* __restrict__ A, const unsigned short* __restrict__ B,
    int M, int N, int K, void* __restrict__ Cv, const float* __restrict__ aux,
    const float* __restrict__ aux2, const unsigned short* __restrict__ auxb) {
  __shared__ char lds[131072];
  const int t = threadIdx.x;
  const int l = t & 63;
  const int wid = t >> 6;
  const int wm = wid >> 2, wn = wid & 3;

  const int nwg = gridDim.x * gridDim.y;
  int bid = blockIdx.y * gridDim.x + blockIdx.x;
  const int chunk = nwg >> 3;
  bid = (bid & 7) * chunk + (bid >> 3);
  const int row0 = (bid / gridDim.x) * 256;
  const int col0 = (bid % gridDim.x) * 256;

  const int NT = K >> 6;
  const int l15 = l & 15, l7 = l & 7, lk = l >> 4;

  f32x4 acc[8][4] = {};
  short8 afA[4][2];
  short8 bfA[2][2];
  short8 bfB[2][2];

  auto stage = [&](const unsigned short* gmat, int tileRow, int kcol, char* region) {
    const int rsub = t >> 3;
    const int csw = ((t & 7) ^ (rsub & 7)) << 3;
    const unsigned short* g0 = gmat + (size_t)(tileRow + rsub) * K + kcol + csw;
    async_lds16(g0, region + (t & ~63) * 16);
    async_lds16(g0 + (size_t)64 * K, region + 8192 + (t & ~63) * 16);
  };

  auto rdA = [&](const char* base, int m, int kh) -> short8 {
    const int r = wm * 64 + m * 16 + l15;
    const int sp = ((((kh << 2) | lk) ^ l7) << 4);
    return *reinterpret_cast<const short8*>(base + r * 128 + sp);
  };
  auto rdB = [&](const char* base, int n, int kh) -> short8 {
    const int r = wn * 32 + n * 16 + l15;
    const int sp = ((((kh << 2) | lk) ^ l7) << 4);
    return *reinterpret_cast<const short8*>(base + r * 128 + sp);
  };

  stage(A, row0,       0, lds + 0);
  stage(A, row0 + 128, 0, lds + 16384);
  stage(B, col0,       0, lds + 32768);
  stage(B, col0 + 128, 0, lds + 49152);
  if (NT > 1) {
    stage(A, row0,       64, lds + 65536 + 0);
    stage(A, row0 + 128, 64, lds + 65536 + 16384);
    stage(B, col0,       64, lds + 65536 + 32768);
    stage(B, col0 + 128, 64, lds + 65536 + 49152);
    asm volatile("s_waitcnt vmcnt(8)" ::: "memory");
  } else {
    asm volatile("s_waitcnt vmcnt(0)" ::: "memory");
  }
  __builtin_amdgcn_s_barrier();
  asm volatile("" ::: "memory");

  #pragma unroll
  for (int n = 0; n < 2; ++n)
    #pragma unroll
    for (int kh = 0; kh < 2; ++kh)
      bfA[n][kh] = rdB(lds + 32768, n, kh);

  for (int tk = 0; tk < NT; ++tk) {
    char* bufC = lds + (tk & 1) * 65536;
    char* bufN = lds + (((tk + 1) & 1) * 65536);
    const bool pf = (tk + 2 < NT);
    const int kpf = (tk + 2) * 64;

    #pragma unroll
    for (int m = 0; m < 4; ++m)
      #pragma unroll
      for (int kh = 0; kh < 2; ++kh)
        afA[m][kh] = rdA(bufC + 0, m, kh);
    __builtin_amdgcn_s_setprio(1);
    #pragma unroll
    for (int kh = 0; kh < 2; ++kh)
      #pragma unroll
      for (int m = 0; m < 4; ++m)
        #pragma unroll
        for (int n = 0; n < 2; ++n)
          acc[m][n] = __builtin_amdgcn_mfma_f32_16x16x32_bf16(afA[m][kh], bfA[n][kh], acc[m][n], 0, 0, 0);
    __builtin_amdgcn_s_setprio(0);
    #pragma unroll
    for (int n = 0; n < 2; ++n)
      #pragma unroll
      for (int kh = 0; kh < 2; ++kh)
        bfB[n][kh] = rdB(bufC + 49152, n, kh);
    asm volatile("" ::: "memory");
    __builtin_amdgcn_s_barrier();
    asm volatile("" ::: "memory");

    __builtin_amdgcn_s_setprio(1);
    #pragma unroll
    for (int kh = 0; kh < 2; ++kh)
      #pragma unroll
      for (int m = 0; m < 4; ++m)
        #pragma unroll
        for (int n = 0; n < 2; ++n)
          acc[m][n + 2] = __builtin_amdgcn_mfma_f32_16x16x32_bf16(afA[m][kh], bfB[n][kh], acc[m][n + 2], 0, 0, 0);
    __builtin_amdgcn_s_setprio(0);
    if (pf) {
      stage(A, row0, kpf, bufC + 0);
      stage(B, col0, kpf, bufC + 32768);
    }
    asm volatile("" ::: "memory");
    __builtin_amdgcn_s_barrier();
    asm volatile("" ::: "memory");

    #pragma unroll
    for (int m = 0; m < 4; ++m)
      #pragma unroll
      for (int kh = 0; kh < 2; ++kh)
        afA[m][kh] = rdA(bufC + 16384, m, kh);
    __builtin_amdgcn_s_setprio(1);
    #pragma unroll
    for (int kh = 0; kh < 2; ++kh)
      #pragma unroll
      for (int m = 0; m < 4; ++m)
        #pragma unroll
        for (int n = 0; n < 2; ++n)
          acc[m + 4][n] = __builtin_amdgcn_mfma_f32_16x16x32_bf16(afA[m][kh], bfA[n][kh], acc[m + 4][n], 0, 0, 0);
    __builtin_amdgcn_s_setprio(0);
    if (pf) stage(B, col0 + 128, kpf, bufC + 49152);
    asm volatile("" ::: "memory");
    __builtin_amdgcn_s_barrier();
    asm volatile("" ::: "memory");

    __builtin_amdgcn_s_setprio(1);
    #pragma unroll
    for (int kh = 0; kh < 2; ++kh)
      #pragma unroll
      for (int m = 0; m < 4; ++m)
        #pragma unroll
        for (int n = 0; n < 2; ++n)
          acc[m + 4][n + 2] = __builtin_amdgcn_mfma_f32_16x16x32_bf16(afA[m][kh], bfB[n][kh], acc[m + 4][n + 2], 0, 0, 0);
    __builtin_amdgcn_s_setprio(0);
    if (pf) stage(A, row0 + 128, kpf, bufC + 16384);
    if (tk + 1 < NT) {
      #pragma unroll
      for (int n = 0; n < 2; ++n)
        #pragma unroll
        for (int kh = 0; kh < 2; ++kh)
          bfA[n][kh] = rdB(bufN + 32768, n, kh);
    }
    if (pf) {
      asm volatile("s_waitcnt vmcnt(4)" ::: "memory");
    } else {
      asm volatile("s_waitcnt vmcnt(0)" ::: "memory");
    }
    __builtin_amdgcn_s_barrier();
    asm volatile("" ::: "memory");
  }
  asm volatile("s_waitcnt vmcnt(0)" ::: "memory");

  const int cr = lk * 4;
  #pragma unroll
  for (int m = 0; m < 8; ++m) {
    const int gr = row0 + ((m >> 2) << 7) + wm * 64 + ((m & 3) << 4) + cr;
    #pragma unroll
    for (int n = 0; n < 4; ++n) {
      const int gc = col0 + ((n >> 1) << 7) + wn * 32 + ((n & 1) << 4) + l15;
      if constexpr (EPI == 2) {
        unsigned short* C = (unsigned short*)Cv;
        const float bb = aux[gc];
        #pragma unroll
        for (int jj = 0; jj < 2; ++jj) {
          const int r = gr + jj * 2;
          float re = acc[m][n][jj * 2] + bb;
          float im = acc[m][n][jj * 2 + 1] + bb;
          float g = 0.5f * re * (1.f + erff(re * 0.70710678118654752440f));
          size_t idx = (size_t)(r >> 1) * 2048 + (size_t)gc * 2;
          unsigned int hv = *(unsigned int*)(C + idx);
          float hx = b2f((unsigned short)(hv & 0xffff));
          float hy = b2f((unsigned short)(hv >> 16));
          hx += 0.1f * g * re;
          hy += 0.1f * g * im;
          unsigned int packed = (unsigned int)f2b(hx) | ((unsigned int)f2b(hy) << 16);
          *(unsigned int*)(C + idx) = packed;
        }
      } else {
        float* C = (float*)Cv;
        const float bb = aux[gc];
        const size_t idx0 = (size_t)(gr >> 1) * 2048 + (size_t)gc * 2;
        float2 v01 = make_float2(acc[m][n][0] + bb, acc[m][n][1] + bb);
        float2 v23 = make_float2(acc[m][n][2] + bb, acc[m][n][3] + bb);
        *(float2*)(C + idx0) = v01;
        *(float2*)(C + idx0 + 2048) = v23;
      }
    }
  }
}

// =====================================================================
// fp8 MX GEMM (unit scales): C = A[M][K] * B[N][K]^T, K in fp8 elements.
// mfma_scale_f32_16x16x128_f8f6f4, scale = 0x7F7F7F7F (1.0 per block).
// K-tile = 128 fp8 elements = 128 B/row -> byte-identical LDS geometry,
// swizzle, staging, and r5 schedule; NT = K/128 (half the bf16 count).
// A frag: row=l&15, k=(l>>4)*32+j (32 consecutive bytes = 2 swizzled b128).
// C/D layout identical to 16x16 bf16 (shape-determined).
// EPI8: 0 = bf16 logits 0.125*acc/(xm*cm+1e-8)   [c pre-scaled x16]
//       1 = bf16 h = residual + 2.44140625e-5*acc [attn x256, c_T x16]
// =====================================================================
template <int EPI8>
__global__ __launch_bounds__(512, 2) void gemm256f8(
    const unsigned char* __restrict__ A, const unsigned char* __restrict__ B,
    int M, int N, int K, void* __restrict__ Cv, const float* __restrict__ aux,
    const float* __restrict__ aux2, const unsigned short* __restrict__ auxb) {
  __shared__ char lds[131072];
  const int t = threadIdx.x;
  const int l = t & 63;
  const int wid = t >> 6;
  const int wm = wid >> 2, wn = wid & 3;

  const int nwg = gridDim.x * gridDim.y;
  int bid = blockIdx.y * gridDim.x + blockIdx.x;
  const int chunk = nwg >> 3;
  bid = (bid & 7) * chunk + (bid >> 3);
  const int row0 = (bid / gridDim.x) * 256;
  const int col0 = (bid % gridDim.x) * 256;

  const int NT = K >> 7;                   // 128-element K-tiles
  const int l15 = l & 15, l7 = l & 7, lk = l >> 4;

  f32x4 acc[8][4] = {};
  int8v a8[4];        // current A half (4 m-frags)
  int8v b0_[2];       // B half0 (2 n-frags)
  int8v b1_[2];       // B half1

  auto stage = [&](const unsigned char* gmat, int tileRow, int kcol, char* region) {
    const int rsub = t >> 3;
    const int csw = ((t & 7) ^ (rsub & 7)) << 4;   // 16B slot, 16 elements
    const unsigned char* g0 = gmat + (size_t)(tileRow + rsub) * K + kcol + csw;
    async_lds16(g0, region + (t & ~63) * 16);
    async_lds16(g0 + (size_t)64 * K, region + 8192 + (t & ~63) * 16);
  };

  auto rdA8 = [&](const char* base, int m) -> int8v {
    union { int8v v; uint4 q[2]; } u;
    const int r = wm * 64 + m * 16 + l15;
    u.q[0] = *(const uint4*)(base + r * 128 + ((((lk << 1) | 0) ^ l7) << 4));
    u.q[1] = *(const uint4*)(base + r * 128 + ((((lk << 1) | 1) ^ l7) << 4));
    return u.v;
  };
  auto rdB8 = [&](const char* base, int n) -> int8v {
    union { int8v v; uint4 q[2]; } u;
    const int r = wn * 32 + n * 16 + l15;
    u.q[0] = *(const uint4*)(base + r * 128 + ((((lk << 1) | 0) ^ l7) << 4));
    u.q[1] = *(const uint4*)(base + r * 128 + ((((lk << 1) | 1) ^ l7) << 4));
    return u.v;
  };

  #define MFMA8(AF, BF, CC) \
    __builtin_amdgcn_mfma_scale_f32_16x16x128_f8f6f4(AF, BF, CC, 0, 0, 0, 0x7F7F7F7F, 0, 0x7F7F7F7F)

  // prologue: stage tiles 0 and 1 fully
  stage(A, row0,       0, lds + 0);
  stage(A, row0 + 128, 0, lds + 16384);
  stage(B, col0,       0, lds + 32768);
  stage(B, col0 + 128, 0, lds + 49152);
  if (NT > 1) {
    stage(A, row0,       128, lds + 65536 + 0);
    stage(A, row0 + 128, 128, lds + 65536 + 16384);
    stage(B, col0,       128, lds + 65536 + 32768);
    stage(B, col0 + 128, 128, lds + 65536 + 49152);
    asm volatile("s_waitcnt vmcnt(8)" ::: "memory");
  } else {
    asm volatile("s_waitcnt vmcnt(0)" ::: "memory");
  }
  __builtin_amdgcn_s_barrier();
  asm volatile("" ::: "memory");

  // pre-read B0 of tile 0
  #pragma unroll
  for (int n = 0; n < 2; ++n) b0_[n] = rdB8(lds + 32768, n);

  for (int tk = 0; tk < NT; ++tk) {
    char* bufC = lds + (tk & 1) * 65536;
    char* bufN = lds + (((tk + 1) & 1) * 65536);
    const bool pf = (tk + 2 < NT);
    const int kpf = (tk + 2) * 128;

    // ---- P0: read A0; MFMA Q00; read B1 ----
    #pragma unroll
    for (int m = 0; m < 4; ++m) a8[m] = rdA8(bufC + 0, m);
    __builtin_amdgcn_s_setprio(1);
    #pragma unroll
    for (int m = 0; m < 4; ++m)
      #pragma unroll
      for (int n = 0; n < 2; ++n)
        acc[m][n] = MFMA8(a8[m], b0_[n], acc[m][n]);
    __builtin_amdgcn_s_setprio(0);
    #pragma unroll
    for (int n = 0; n < 2; ++n) b1_[n] = rdB8(bufC + 49152, n);
    asm volatile("" ::: "memory");
    __builtin_amdgcn_s_barrier();
    asm volatile("" ::: "memory");

    // ---- P1: MFMA Q01; stage A0,B0(t+2) ----
    __builtin_amdgcn_s_setprio(1);
    #pragma unroll
    for (int m = 0; m < 4; ++m)
      #pragma unroll
      for (int n = 0; n < 2; ++n)
        acc[m][n + 2] = MFMA8(a8[m], b1_[n], acc[m][n + 2]);
    __builtin_amdgcn_s_setprio(0);
    if (pf) {
      stage(A, row0, kpf, bufC + 0);
      stage(B, col0, kpf, bufC + 32768);
    }
    asm volatile("" ::: "memory");
    __builtin_amdgcn_s_barrier();
    asm volatile("" ::: "memory");

    // ---- P2: read A1 (overwrite a8); MFMA Q10; stage B1(t+2) ----
    #pragma unroll
    for (int m = 0; m < 4; ++m) a8[m] = rdA8(bufC + 16384, m);
    __builtin_amdgcn_s_setprio(1);
    #pragma unroll
    for (int m = 0; m < 4; ++m)
      #pragma unroll
      for (int n = 0; n < 2; ++n)
        acc[m + 4][n] = MFMA8(a8[m], b0_[n], acc[m + 4][n]);
    __builtin_amdgcn_s_setprio(0);
    if (pf) stage(B, col0 + 128, kpf, bufC + 49152);
    asm volatile("" ::: "memory");
    __builtin_amdgcn_s_barrier();
    asm volatile("" ::: "memory");

    // ---- P3: MFMA Q11; stage A1(t+2); read B0(t+1); vmcnt(4); barrier ----
    __builtin_amdgcn_s_setprio(1);
    #pragma unroll
    for (int m = 0; m < 4; ++m)
      #pragma unroll
      for (int n = 0; n < 2; ++n)
        acc[m + 4][n + 2] = MFMA8(a8[m], b1_[n], acc[m + 4][n + 2]);
    __builtin_amdgcn_s_setprio(0);
    if (pf) stage(A, row0 + 128, kpf, bufC + 16384);
    if (tk + 1 < NT) {
      #pragma unroll
      for (int n = 0; n < 2; ++n) b0_[n] = rdB8(bufN + 32768, n);
    }
    if (pf) {
      asm volatile("s_waitcnt vmcnt(4)" ::: "memory");
    } else {
      asm volatile("s_waitcnt vmcnt(0)" ::: "memory");
    }
    __builtin_amdgcn_s_barrier();
    asm volatile("" ::: "memory");
  }
  asm volatile("s_waitcnt vmcnt(0)" ::: "memory");
  #undef MFMA8

  // ---- epilogue (C/D layout same as 16x16 bf16) ----
  const int cr = lk * 4;
  #pragma unroll
  for (int m = 0; m < 8; ++m) {
    const int gr = row0 + ((m >> 2) << 7) + wm * 64 + ((m & 3) << 4) + cr;
    #pragma unroll
    for (int n = 0; n < 4; ++n) {
      const int gc = col0 + ((n >> 1) << 7) + wn * 32 + ((n & 1) << 4) + l15;
      if constexpr (EPI8 == 0) {
        unsigned short* C = (unsigned short*)Cv;
        const float cm_ = aux2[gc];
        #pragma unroll
        for (int j = 0; j < 4; ++j) {
          const int r = gr + j;
          float v = 0.125f * acc[m][n][j] / (aux[r] * cm_ + 1e-8f);
          C[(size_t)r * N + gc] = f2b(v);
        }
      } else {
        unsigned short* C = (unsigned short*)Cv;
        #pragma unroll
        for (int j = 0; j < 4; ++j) {
          const int r = gr + j;
          C[(size_t)r * N + gc] = f2b(b2f(auxb[(size_t)r * N + gc]) + 2.44140625e-5f * acc[m][n][j]);
        }
      }
    }
  }
}

extern "C" void kernel_launch(void* const* d_in, const int* in_sizes, int n_in,
                              void* d_out, int out_size, void* d_ws, size_t ws_size,
                              hipStream_t stream) {
  const float* x     = (const float*)d_in[0];
  const float* cm    = (const float*)d_in[1];
  const float* Wl    = (const float*)d_in[2];
  const float* bl    = (const float*)d_in[3];
  const float* gamma = (const float*)d_in[4];
  const float* beta  = (const float*)d_in[5];
  const float* Wo    = (const float*)d_in[6];
  const float* bo    = (const float*)d_in[7];
  const float* go    = (const float*)d_in[8];
  const float* bto   = (const float*)d_in[9];
  float* out = (float*)d_out;

  char* p = (char*)d_ws;
  unsigned short* x_bf  = (unsigned short*)p; p += (size_t)ROWS * K2 * 2;   // 33.5MB
  unsigned char*  x_f8  = (unsigned char*)p;  p += (size_t)ROWS * K2;       // 16.8MB
  unsigned char*  c_f8  = (unsigned char*)p;  p += (size_t)NCPT * K2;       // 4.2MB (x16)
  unsigned char*  cT_f8 = (unsigned char*)p;  p += (size_t)K2 * NCPT;       // 4.2MB (x16)
  unsigned short* w_bf  = (unsigned short*)p; p += (size_t)3 * 1024 * 1024 * 2;
  float* x_mag = (float*)p; p += (size_t)ROWS * 4;
  float* c_mag = (float*)p; p += (size_t)NCPT * 4;
  unsigned short* dot_bf = (unsigned short*)p; p += (size_t)ROWS * NCPT * 2; // 33.5MB
  unsigned char*  attn_f8 = (unsigned char*)p; p += (size_t)ROWS * NCPT;     // 16.8MB (x256)
  unsigned short* h      = (unsigned short*)p; p += (size_t)ROWS * K2 * 2;   // 33.5MB
  unsigned short* ln_bf = dot_bf;  // reuse logits region after softmax

  // prep
  cast_row_mag<<<ROWS, 256, 0, stream>>>(x, x_bf, x_f8, 1.f, x_mag, K2);
  cast_row_mag<<<NCPT, 256, 0, stream>>>(cm, nullptr, c_f8, 16.f, c_mag, K2);
  transpose_f8<<<dim3(64, 64), 256, 0, stream>>>(cm, cT_f8, 2048);
  cast_w<<<1536, 256, 0, stream>>>(Wl, Wo, w_bf);

  // concept attention (fp8 MX GEMMs)
  gemm256f8<0><<<dim3(NCPT / 256, ROWS / 256), 512, 0, stream>>>(
      x_f8, c_f8, ROWS, NCPT, K2, dot_bf, x_mag, c_mag, nullptr);
  softmax_attn<<<ROWS, 256, 0, stream>>>(dot_bf, attn_f8);
  gemm256f8<1><<<dim3(K2 / 256, ROWS / 256), 512, 0, stream>>>(
      attn_f8, cT_f8, ROWS, K2, NCPT, h, nullptr, nullptr, x_bf);

  // gated FFN blocks (bf16 GEMM, fused gelu-gate + residual RMW)
  for (int l = 0; l < 2; ++l) {
    phase_ln<<<ROWS, 256, 0, stream>>>(h, gamma + l * 1024, beta + l * 1024, ln_bf);
    gemm256<2><<<dim3(DIMD / 256, 2 * ROWS / 256), 512, 0, stream>>>(
        ln_bf, w_bf + (size_t)l * 1024 * 1024, 2 * ROWS, DIMD, DIMD, h, bl + l * 1024, nullptr, nullptr);
  }

  // output projection (bf16 GEMM)
  phase_ln<<<ROWS, 256, 0, stream>>>(h, go, bto, ln_bf);
  gemm256<3><<<dim3(DIMD / 256, 2 * ROWS / 256), 512, 0, stream>>>(
      ln_bf, w_bf + 2 * 1024 * 1024, 2 * ROWS, DIMD, DIMD, out, bo, nullptr, nullptr);
}

// Round 15
// 342.228 us; speedup vs baseline: 1.0649x; 1.0649x over previous
//
#include <hip/hip_runtime.h>
#include <hip/hip_bf16.h>
#include <hip/hip_fp8.h>

#define ROWS 8192      // B*S
#define K2   2048      // 2*DIM
#define NCPT 2048
#define DIMD 1024

using short8 = __attribute__((ext_vector_type(8))) short;
using f32x4  = __attribute__((ext_vector_type(4))) float;
using int4v  = __attribute__((ext_vector_type(4))) int;
using int8v  = __attribute__((ext_vector_type(8))) int;

__device__ __forceinline__ unsigned short f2b(float f) {
  __hip_bfloat16 h = __float2bfloat16(f);
  return *reinterpret_cast<unsigned short*>(&h);
}
__device__ __forceinline__ float b2f(unsigned short u) {
  unsigned int x = ((unsigned int)u) << 16;
  return __uint_as_float(x);
}
__device__ __forceinline__ unsigned char f2f8(float f) {
  __hip_fp8_e4m3 h(f);
  return (unsigned char)h.__x;
}

__device__ __forceinline__ void store_bf16x8(unsigned short* dst, const float4& a, const float4& b) {
  union { unsigned short u[8]; uint4 q; } p;
  p.u[0]=f2b(a.x); p.u[1]=f2b(a.y); p.u[2]=f2b(a.z); p.u[3]=f2b(a.w);
  p.u[4]=f2b(b.x); p.u[5]=f2b(b.y); p.u[6]=f2b(b.z); p.u[7]=f2b(b.w);
  *reinterpret_cast<uint4*>(dst) = p.q;
}
__device__ __forceinline__ void store_bf16x4(unsigned short* dst, float a, float b, float c, float d) {
  union { unsigned short u[4]; uint2 q; } p;
  p.u[0]=f2b(a); p.u[1]=f2b(b); p.u[2]=f2b(c); p.u[3]=f2b(d);
  *reinterpret_cast<uint2*>(dst) = p.q;
}
__device__ __forceinline__ void store_fp8x8(unsigned char* dst, const float4& a, const float4& b, float s) {
  union { unsigned char c[8]; uint2 q; } p;
  p.c[0]=f2f8(a.x*s); p.c[1]=f2f8(a.y*s); p.c[2]=f2f8(a.z*s); p.c[3]=f2f8(a.w*s);
  p.c[4]=f2f8(b.x*s); p.c[5]=f2f8(b.y*s); p.c[6]=f2f8(b.z*s); p.c[7]=f2f8(b.w*s);
  *reinterpret_cast<uint2*>(dst) = p.q;
}

__device__ __forceinline__ void async_lds16(const void* g, void* l) {
  __builtin_amdgcn_global_load_lds((__attribute__((address_space(1))) void*)g,
                                   (__attribute__((address_space(3))) void*)l, 16, 0, 0);
}

// ---------------- cast (bf16 optional + fp8 scaled) + row magnitude ----------------
__global__ void cast_row_mag(const float* __restrict__ src, unsigned short* __restrict__ dst_bf,
                             unsigned char* __restrict__ dst_f8, float fscale,
                             float* __restrict__ mag, int ncol) {
  __shared__ float sred[4];
  int row = blockIdx.x, t = threadIdx.x;
  const float* s = src + (size_t)row * ncol;
  float ss = 0.f;
  for (int i = t * 8; i < ncol; i += 2048) {
    float4 a = *(const float4*)(s + i);
    float4 b = *(const float4*)(s + i + 4);
    ss += a.x*a.x + a.y*a.y + a.z*a.z + a.w*a.w;
    ss += b.x*b.x + b.y*b.y + b.z*b.z + b.w*b.w;
    if (dst_bf) store_bf16x8(dst_bf + (size_t)row * ncol + i, a, b);
    store_fp8x8(dst_f8 + (size_t)row * ncol + i, a, b, fscale);
  }
  int lane = t & 63, w = t >> 6;
  for (int o = 32; o; o >>= 1) ss += __shfl_down(ss, o);
  if (lane == 0) sred[w] = ss;
  __syncthreads();
  if (t == 0) mag[row] = sqrtf(sred[0] + sred[1] + sred[2] + sred[3] + 1e-8f);
}

// ---------------- fused fp32 -> bf16 cast for Wl (2M) + Wo (1M) ----------------
__global__ void cast_w(const float* __restrict__ wl, const float* __restrict__ wo,
                       unsigned short* __restrict__ dst) {
  int b = blockIdx.x;
  const float* src;
  unsigned short* d;
  if (b < 1024) { src = wl + (size_t)b * 2048; d = dst + (size_t)b * 2048; }
  else {
    src = wo + (size_t)(b - 1024) * 2048;
    d = dst + (size_t)2 * 1024 * 1024 + (size_t)(b - 1024) * 2048;
  }
  int i = threadIdx.x * 8;
  float4 a = *(const float4*)(src + i);
  float4 c = *(const float4*)(src + i + 4);
  store_bf16x8(d + i, a, c);
}

// ---------------- transpose fp32 [n][n] -> fp8 (x16) [n][n]^T ----------------
__global__ void transpose_f8(const float* __restrict__ src, unsigned char* __restrict__ dst, int n) {
  __shared__ float tile[32][33];
  int bx = blockIdx.x * 32;
  int by = blockIdx.y * 32;
  int tx = threadIdx.x & 31, ty = threadIdx.x >> 5;
  #pragma unroll
  for (int i = ty; i < 32; i += 8)
    tile[i][tx] = src[(size_t)(by + i) * n + bx + tx];
  __syncthreads();
  #pragma unroll
  for (int i = ty; i < 32; i += 8)
    dst[(size_t)(bx + i) * n + by + tx] = f2f8(16.f * tile[tx][i]);
}

// ---------------- softmax over concepts (bf16 logits in, fp8 x256 attn out) ----------------
__global__ void softmax_attn(const unsigned short* __restrict__ logit, unsigned char* __restrict__ attn) {
  __shared__ float sred[4];
  int row = blockIdx.x, t = threadIdx.x;
  int lane = t & 63, w = t >> 6;
  const unsigned short* lr = logit + (size_t)row * NCPT + t * 8;
  short8 lv = *reinterpret_cast<const short8*>(lr);
  float l[8];
  #pragma unroll
  for (int i = 0; i < 8; ++i) l[i] = b2f((unsigned short)lv[i]);
  float m = l[0];
  #pragma unroll
  for (int i = 1; i < 8; ++i) m = fmaxf(m, l[i]);
  for (int o = 32; o; o >>= 1) m = fmaxf(m, __shfl_down(m, o));
  if (lane == 0) sred[w] = m;
  __syncthreads();
  m = fmaxf(fmaxf(sred[0], sred[1]), fmaxf(sred[2], sred[3]));
  __syncthreads();
  float e[8], s = 0.f;
  #pragma unroll
  for (int i = 0; i < 8; ++i) { e[i] = expf(l[i] - m); s += e[i]; }
  for (int o = 32; o; o >>= 1) s += __shfl_down(s, o);
  if (lane == 0) sred[w] = s;
  __syncthreads();
  s = sred[0] + sred[1] + sred[2] + sred[3];
  float inv = 256.f / s;   // x256 folded into the normalization
  float4 A = make_float4(e[0]*inv, e[1]*inv, e[2]*inv, e[3]*inv);
  float4 B = make_float4(e[4]*inv, e[5]*inv, e[6]*inv, e[7]*inv);
  store_fp8x8(attn + (size_t)row * NCPT + t * 8, A, B, 1.f);
}

// ---------------- per-component LayerNorm (bf16 h in); de-interleaves to bf16 rows ----------------
__global__ void phase_ln(const unsigned short* __restrict__ h, const float* __restrict__ gamma,
                         const float* __restrict__ beta, unsigned short* __restrict__ out) {
  __shared__ float4 s4[4];
  int bs = blockIdx.x, t = threadIdx.x;
  const unsigned short* hr = h + (size_t)bs * 2048 + t * 8;
  short8 hv = *reinterpret_cast<const short8*>(hr);
  float r0 = b2f((unsigned short)hv[0]), i0 = b2f((unsigned short)hv[1]);
  float r1 = b2f((unsigned short)hv[2]), i1 = b2f((unsigned short)hv[3]);
  float r2 = b2f((unsigned short)hv[4]), i2 = b2f((unsigned short)hv[5]);
  float r3 = b2f((unsigned short)hv[6]), i3 = b2f((unsigned short)hv[7]);
  float4 s;
  s.x = r0 + r1 + r2 + r3;
  s.y = r0*r0 + r1*r1 + r2*r2 + r3*r3;
  s.z = i0 + i1 + i2 + i3;
  s.w = i0*i0 + i1*i1 + i2*i2 + i3*i3;
  int lane = t & 63, w = t >> 6;
  for (int o = 32; o; o >>= 1) {
    s.x += __shfl_down(s.x, o); s.y += __shfl_down(s.y, o);
    s.z += __shfl_down(s.z, o); s.w += __shfl_down(s.w, o);
  }
  if (lane == 0) s4[w] = s;
  __syncthreads();
  float4 T = s4[0];
  #pragma unroll
  for (int i = 1; i < 4; ++i) { T.x += s4[i].x; T.y += s4[i].y; T.z += s4[i].z; T.w += s4[i].w; }
  const float invd = 1.f / 1024.f;
  float mu_r = T.x * invd, var_r = T.y * invd - mu_r * mu_r;
  float mu_i = T.z * invd, var_i = T.w * invd - mu_i * mu_i;
  float is_r = 1.f / sqrtf(var_r + 1e-5f);
  float is_i = 1.f / sqrtf(var_i + 1e-5f);
  float4 g = *(const float4*)(gamma + t * 4);
  float4 b = *(const float4*)(beta + t * 4);
  unsigned short* o0 = out + (size_t)(2 * bs) * 1024 + t * 4;
  unsigned short* o1 = out + (size_t)(2 * bs + 1) * 1024 + t * 4;
  store_bf16x4(o0, (r0-mu_r)*is_r*g.x + b.x, (r1-mu_r)*is_r*g.y + b.y,
                   (r2-mu_r)*is_r*g.z + b.z, (r3-mu_r)*is_r*g.w + b.w);
  store_bf16x4(o1, (i0-mu_i)*is_i*g.x + b.x, (i1-mu_i)*is_i*g.y + b.y,
                   (i2-mu_i)*is_i*g.z + b.z, (i3-mu_i)*is_i*g.w + b.w);
}

// =====================================================================
// bf16 GEMM (r5 core, unchanged): used for EPI 2 (FFN) and 3 (out).
// =====================================================================
template <int EPI>
__global__ __launch_bounds__(512, 2) void gemm256(
    const unsigned short* __restrict__ A, const unsigned short* __restrict__ B,
    int M, int N, int K, void* __restrict__ Cv, const float* __restrict__ aux,
    const float* __restrict__ aux2, const unsigned short* __restrict__ auxb) {
  __shared__ char lds[131072];
  const int t = threadIdx.x;
  const int l = t & 63;
  const int wid = t >> 6;
  const int wm = wid >> 2, wn = wid & 3;

  const int nwg = gridDim.x * gridDim.y;
  int bid = blockIdx.y * gridDim.x + blockIdx.x;
  const int chunk = nwg >> 3;
  bid = (bid & 7) * chunk + (bid >> 3);
  const int row0 = (bid / gridDim.x) * 256;
  const int col0 = (bid % gridDim.x) * 256;

  const int NT = K >> 6;
  const int l15 = l & 15, l7 = l & 7, lk = l >> 4;

  f32x4 acc[8][4] = {};
  short8 afA[4][2];
  short8 bfA[2][2];
  short8 bfB[2][2];

  auto stage = [&](const unsigned short* gmat, int tileRow, int kcol, char* region) {
    const int rsub = t >> 3;
    const int csw = ((t & 7) ^ (rsub & 7)) << 3;
    const unsigned short* g0 = gmat + (size_t)(tileRow + rsub) * K + kcol + csw;
    async_lds16(g0, region + (t & ~63) * 16);
    async_lds16(g0 + (size_t)64 * K, region + 8192 + (t & ~63) * 16);
  };

  auto rdA = [&](const char* base, int m, int kh) -> short8 {
    const int r = wm * 64 + m * 16 + l15;
    const int sp = ((((kh << 2) | lk) ^ l7) << 4);
    return *reinterpret_cast<const short8*>(base + r * 128 + sp);
  };
  auto rdB = [&](const char* base, int n, int kh) -> short8 {
    const int r = wn * 32 + n * 16 + l15;
    const int sp = ((((kh << 2) | lk) ^ l7) << 4);
    return *reinterpret_cast<const short8*>(base + r * 128 + sp);
  };

  stage(A, row0,       0, lds + 0);
  stage(A, row0 + 128, 0, lds + 16384);
  stage(B, col0,       0, lds + 32768);
  stage(B, col0 + 128, 0, lds + 49152);
  if (NT > 1) {
    stage(A, row0,       64, lds + 65536 + 0);
    stage(A, row0 + 128, 64, lds + 65536 + 16384);
    stage(B, col0,       64, lds + 65536 + 32768);
    stage(B, col0 + 128, 64, lds + 65536 + 49152);
    asm volatile("s_waitcnt vmcnt(8)" ::: "memory");
  } else {
    asm volatile("s_waitcnt vmcnt(0)" ::: "memory");
  }
  __builtin_amdgcn_s_barrier();
  asm volatile("" ::: "memory");

  #pragma unroll
  for (int n = 0; n < 2; ++n)
    #pragma unroll
    for (int kh = 0; kh < 2; ++kh)
      bfA[n][kh] = rdB(lds + 32768, n, kh);

  for (int tk = 0; tk < NT; ++tk) {
    char* bufC = lds + (tk & 1) * 65536;
    char* bufN = lds + (((tk + 1) & 1) * 65536);
    const bool pf = (tk + 2 < NT);
    const int kpf = (tk + 2) * 64;

    #pragma unroll
    for (int m = 0; m < 4; ++m)
      #pragma unroll
      for (int kh = 0; kh < 2; ++kh)
        afA[m][kh] = rdA(bufC + 0, m, kh);
    __builtin_amdgcn_s_setprio(1);
    #pragma unroll
    for (int kh = 0; kh < 2; ++kh)
      #pragma unroll
      for (int m = 0; m < 4; ++m)
        #pragma unroll
        for (int n = 0; n < 2; ++n)
          acc[m][n] = __builtin_amdgcn_mfma_f32_16x16x32_bf16(afA[m][kh], bfA[n][kh], acc[m][n], 0, 0, 0);
    __builtin_amdgcn_s_setprio(0);
    #pragma unroll
    for (int n = 0; n < 2; ++n)
      #pragma unroll
      for (int kh = 0; kh < 2; ++kh)
        bfB[n][kh] = rdB(bufC + 49152, n, kh);
    asm volatile("" ::: "memory");
    __builtin_amdgcn_s_barrier();
    asm volatile("" ::: "memory");

    __builtin_amdgcn_s_setprio(1);
    #pragma unroll
    for (int kh = 0; kh < 2; ++kh)
      #pragma unroll
      for (int m = 0; m < 4; ++m)
        #pragma unroll
        for (int n = 0; n < 2; ++n)
          acc[m][n + 2] = __builtin_amdgcn_mfma_f32_16x16x32_bf16(afA[m][kh], bfB[n][kh], acc[m][n + 2], 0, 0, 0);
    __builtin_amdgcn_s_setprio(0);
    if (pf) {
      stage(A, row0, kpf, bufC + 0);
      stage(B, col0, kpf, bufC + 32768);
    }
    asm volatile("" ::: "memory");
    __builtin_amdgcn_s_barrier();
    asm volatile("" ::: "memory");

    #pragma unroll
    for (int m = 0; m < 4; ++m)
      #pragma unroll
      for (int kh = 0; kh < 2; ++kh)
        afA[m][kh] = rdA(bufC + 16384, m, kh);
    __builtin_amdgcn_s_setprio(1);
    #pragma unroll
    for (int kh = 0; kh < 2; ++kh)
      #pragma unroll
      for (int m = 0; m < 4; ++m)
        #pragma unroll
        for (int n = 0; n < 2; ++n)
          acc[m + 4][n] = __builtin_amdgcn_mfma_f32_16x16x32_bf16(afA[m][kh], bfA[n][kh], acc[m + 4][n], 0, 0, 0);
    __builtin_amdgcn_s_setprio(0);
    if (pf) stage(B, col0 + 128, kpf, bufC + 49152);
    asm volatile("" ::: "memory");
    __builtin_amdgcn_s_barrier();
    asm volatile("" ::: "memory");

    __builtin_amdgcn_s_setprio(1);
    #pragma unroll
    for (int kh = 0; kh < 2; ++kh)
      #pragma unroll
      for (int m = 0; m < 4; ++m)
        #pragma unroll
        for (int n = 0; n < 2; ++n)
          acc[m + 4][n + 2] = __builtin_amdgcn_mfma_f32_16x16x32_bf16(afA[m][kh], bfB[n][kh], acc[m + 4][n + 2], 0, 0, 0);
    __builtin_amdgcn_s_setprio(0);
    if (pf) stage(A, row0 + 128, kpf, bufC + 16384);
    if (tk + 1 < NT) {
      #pragma unroll
      for (int n = 0; n < 2; ++n)
        #pragma unroll
        for (int kh = 0; kh < 2; ++kh)
          bfA[n][kh] = rdB(bufN + 32768, n, kh);
    }
    if (pf) {
      asm volatile("s_waitcnt vmcnt(4)" ::: "memory");
    } else {
      asm volatile("s_waitcnt vmcnt(0)" ::: "memory");
    }
    __builtin_amdgcn_s_barrier();
    asm volatile("" ::: "memory");
  }
  asm volatile("s_waitcnt vmcnt(0)" ::: "memory");

  const int cr = lk * 4;
  #pragma unroll
  for (int m = 0; m < 8; ++m) {
    const int gr = row0 + ((m >> 2) << 7) + wm * 64 + ((m & 3) << 4) + cr;
    #pragma unroll
    for (int n = 0; n < 4; ++n) {
      const int gc = col0 + ((n >> 1) << 7) + wn * 32 + ((n & 1) << 4) + l15;
      if constexpr (EPI == 2) {
        unsigned short* C = (unsigned short*)Cv;
        const float bb = aux[gc];
        #pragma unroll
        for (int jj = 0; jj < 2; ++jj) {
          const int r = gr + jj * 2;
          float re = acc[m][n][jj * 2] + bb;
          float im = acc[m][n][jj * 2 + 1] + bb;
          float g = 0.5f * re * (1.f + erff(re * 0.70710678118654752440f));
          size_t idx = (size_t)(r >> 1) * 2048 + (size_t)gc * 2;
          unsigned int hv = *(unsigned int*)(C + idx);
          float hx = b2f((unsigned short)(hv & 0xffff));
          float hy = b2f((unsigned short)(hv >> 16));
          hx += 0.1f * g * re;
          hy += 0.1f * g * im;
          unsigned int packed = (unsigned int)f2b(hx) | ((unsigned int)f2b(hy) << 16);
          *(unsigned int*)(C + idx) = packed;
        }
      } else {
        float* C = (float*)Cv;
        const float bb = aux[gc];
        const size_t idx0 = (size_t)(gr >> 1) * 2048 + (size_t)gc * 2;
        float2 v01 = make_float2(acc[m][n][0] + bb, acc[m][n][1] + bb);
        float2 v23 = make_float2(acc[m][n][2] + bb, acc[m][n][3] + bb);
        *(float2*)(C + idx0) = v01;
        *(float2*)(C + idx0 + 2048) = v23;
      }
    }
  }
}

// =====================================================================
// fp8 MX GEMM (unit scales): C = A[M][K] * B[N][K]^T, K in fp8 elements.
// mfma_scale_f32_16x16x128_f8f6f4, scale = 0x7F7F7F7F (1.0 per block).
// Fragment assembly via __builtin_shufflevector (register-resident; the
// r14 union-based assembly was the suspected scratch round-trip).
// EPI8: 0 = bf16 logits 0.125*acc/(xm*cm+1e-8)   [c pre-scaled x16]
//       1 = bf16 h = residual + 2.44140625e-5*acc [attn x256, c_T x16]
// =====================================================================
template <int EPI8>
__global__ __launch_bounds__(512, 2) void gemm256f8(
    const unsigned char* __restrict__ A, const unsigned char* __restrict__ B,
    int M, int N, int K, void* __restrict__ Cv, const float* __restrict__ aux,
    const float* __restrict__ aux2, const unsigned short* __restrict__ auxb) {
  __shared__ char lds[131072];
  const int t = threadIdx.x;
  const int l = t & 63;
  const int wid = t >> 6;
  const int wm = wid >> 2, wn = wid & 3;

  const int nwg = gridDim.x * gridDim.y;
  int bid = blockIdx.y * gridDim.x + blockIdx.x;
  const int chunk = nwg >> 3;
  bid = (bid & 7) * chunk + (bid >> 3);
  const int row0 = (bid / gridDim.x) * 256;
  const int col0 = (bid % gridDim.x) * 256;

  const int NT = K >> 7;                   // 128-element K-tiles
  const int l15 = l & 15, l7 = l & 7, lk = l >> 4;

  f32x4 acc[8][4] = {};
  int8v a8[4];
  int8v b0_[2];
  int8v b1_[2];

  auto stage = [&](const unsigned char* gmat, int tileRow, int kcol, char* region) {
    const int rsub = t >> 3;
    const int csw = ((t & 7) ^ (rsub & 7)) << 4;   // 16B slot, 16 fp8 elements
    const unsigned char* g0 = gmat + (size_t)(tileRow + rsub) * K + kcol + csw;
    async_lds16(g0, region + (t & ~63) * 16);
    async_lds16(g0 + (size_t)64 * K, region + 8192 + (t & ~63) * 16);
  };

  auto rdA8 = [&](const char* base, int m) -> int8v {
    const int r = wm * 64 + m * 16 + l15;
    int4v q0 = *reinterpret_cast<const int4v*>(base + r * 128 + ((((lk << 1) | 0) ^ l7) << 4));
    int4v q1 = *reinterpret_cast<const int4v*>(base + r * 128 + ((((lk << 1) | 1) ^ l7) << 4));
    return __builtin_shufflevector(q0, q1, 0, 1, 2, 3, 4, 5, 6, 7);
  };
  auto rdB8 = [&](const char* base, int n) -> int8v {
    const int r = wn * 32 + n * 16 + l15;
    int4v q0 = *reinterpret_cast<const int4v*>(base + r * 128 + ((((lk << 1) | 0) ^ l7) << 4));
    int4v q1 = *reinterpret_cast<const int4v*>(base + r * 128 + ((((lk << 1) | 1) ^ l7) << 4));
    return __builtin_shufflevector(q0, q1, 0, 1, 2, 3, 4, 5, 6, 7);
  };

  #define MFMA8(AF, BF, CC) \
    __builtin_amdgcn_mfma_scale_f32_16x16x128_f8f6f4(AF, BF, CC, 0, 0, 0, 0x7F7F7F7F, 0, 0x7F7F7F7F)

  // prologue: stage tiles 0 and 1 fully
  stage(A, row0,       0, lds + 0);
  stage(A, row0 + 128, 0, lds + 16384);
  stage(B, col0,       0, lds + 32768);
  stage(B, col0 + 128, 0, lds + 49152);
  if (NT > 1) {
    stage(A, row0,       128, lds + 65536 + 0);
    stage(A, row0 + 128, 128, lds + 65536 + 16384);
    stage(B, col0,       128, lds + 65536 + 32768);
    stage(B, col0 + 128, 128, lds + 65536 + 49152);
    asm volatile("s_waitcnt vmcnt(8)" ::: "memory");
  } else {
    asm volatile("s_waitcnt vmcnt(0)" ::: "memory");
  }
  __builtin_amdgcn_s_barrier();
  asm volatile("" ::: "memory");

  // pre-read B0 of tile 0
  #pragma unroll
  for (int n = 0; n < 2; ++n) b0_[n] = rdB8(lds + 32768, n);

  for (int tk = 0; tk < NT; ++tk) {
    char* bufC = lds + (tk & 1) * 65536;
    char* bufN = lds + (((tk + 1) & 1) * 65536);
    const bool pf = (tk + 2 < NT);
    const int kpf = (tk + 2) * 128;

    // ---- P0: read A0; MFMA Q00; read B1 ----
    #pragma unroll
    for (int m = 0; m < 4; ++m) a8[m] = rdA8(bufC + 0, m);
    __builtin_amdgcn_s_setprio(1);
    #pragma unroll
    for (int m = 0; m < 4; ++m)
      #pragma unroll
      for (int n = 0; n < 2; ++n)
        acc[m][n] = MFMA8(a8[m], b0_[n], acc[m][n]);
    __builtin_amdgcn_s_setprio(0);
    #pragma unroll
    for (int n = 0; n < 2; ++n) b1_[n] = rdB8(bufC + 49152, n);
    asm volatile("" ::: "memory");
    __builtin_amdgcn_s_barrier();
    asm volatile("" ::: "memory");

    // ---- P1: MFMA Q01; stage A0,B0(t+2) ----
    __builtin_amdgcn_s_setprio(1);
    #pragma unroll
    for (int m = 0; m < 4; ++m)
      #pragma unroll
      for (int n = 0; n < 2; ++n)
        acc[m][n + 2] = MFMA8(a8[m], b1_[n], acc[m][n + 2]);
    __builtin_amdgcn_s_setprio(0);
    if (pf) {
      stage(A, row0, kpf, bufC + 0);
      stage(B, col0, kpf, bufC + 32768);
    }
    asm volatile("" ::: "memory");
    __builtin_amdgcn_s_barrier();
    asm volatile("" ::: "memory");

    // ---- P2: read A1 (overwrite a8); MFMA Q10; stage B1(t+2) ----
    #pragma unroll
    for (int m = 0; m < 4; ++m) a8[m] = rdA8(bufC + 16384, m);
    __builtin_amdgcn_s_setprio(1);
    #pragma unroll
    for (int m = 0; m < 4; ++m)
      #pragma unroll
      for (int n = 0; n < 2; ++n)
        acc[m + 4][n] = MFMA8(a8[m], b0_[n], acc[m + 4][n]);
    __builtin_amdgcn_s_setprio(0);
    if (pf) stage(B, col0 + 128, kpf, bufC + 49152);
    asm volatile("" ::: "memory");
    __builtin_amdgcn_s_barrier();
    asm volatile("" ::: "memory");

    // ---- P3: MFMA Q11; stage A1(t+2); read B0(t+1); vmcnt(4); barrier ----
    __builtin_amdgcn_s_setprio(1);
    #pragma unroll
    for (int m = 0; m < 4; ++m)
      #pragma unroll
      for (int n = 0; n < 2; ++n)
        acc[m + 4][n + 2] = MFMA8(a8[m], b1_[n], acc[m + 4][n + 2]);
    __builtin_amdgcn_s_setprio(0);
    if (pf) stage(A, row0 + 128, kpf, bufC + 16384);
    if (tk + 1 < NT) {
      #pragma unroll
      for (int n = 0; n < 2; ++n) b0_[n] = rdB8(bufN + 32768, n);
    }
    if (pf) {
      asm volatile("s_waitcnt vmcnt(4)" ::: "memory");
    } else {
      asm volatile("s_waitcnt vmcnt(0)" ::: "memory");
    }
    __builtin_amdgcn_s_barrier();
    asm volatile("" ::: "memory");
  }
  asm volatile("s_waitcnt vmcnt(0)" ::: "memory");
  #undef MFMA8

  // ---- epilogue (C/D layout same as 16x16 bf16) ----
  const int cr = lk * 4;
  #pragma unroll
  for (int m = 0; m < 8; ++m) {
    const int gr = row0 + ((m >> 2) << 7) + wm * 64 + ((m & 3) << 4) + cr;
    #pragma unroll
    for (int n = 0; n < 4; ++n) {
      const int gc = col0 + ((n >> 1) << 7) + wn * 32 + ((n & 1) << 4) + l15;
      if constexpr (EPI8 == 0) {
        unsigned short* C = (unsigned short*)Cv;
        const float cm_ = aux2[gc];
        #pragma unroll
        for (int j = 0; j < 4; ++j) {
          const int r = gr + j;
          float v = 0.125f * acc[m][n][j] / (aux[r] * cm_ + 1e-8f);
          C[(size_t)r * N + gc] = f2b(v);
        }
      } else {
        unsigned short* C = (unsigned short*)Cv;
        #pragma unroll
        for (int j = 0; j < 4; ++j) {
          const int r = gr + j;
          C[(size_t)r * N + gc] = f2b(b2f(auxb[(size_t)r * N + gc]) + 2.44140625e-5f * acc[m][n][j]);
        }
      }
    }
  }
}

extern "C" void kernel_launch(void* const* d_in, const int* in_sizes, int n_in,
                              void* d_out, int out_size, void* d_ws, size_t ws_size,
                              hipStream_t stream) {
  const float* x     = (const float*)d_in[0];
  const float* cm    = (const float*)d_in[1];
  const float* Wl    = (const float*)d_in[2];
  const float* bl    = (const float*)d_in[3];
  const float* gamma = (const float*)d_in[4];
  const float* beta  = (const float*)d_in[5];
  const float* Wo    = (const float*)d_in[6];
  const float* bo    = (const float*)d_in[7];
  const float* go    = (const float*)d_in[8];
  const float* bto   = (const float*)d_in[9];
  float* out = (float*)d_out;

  char* p = (char*)d_ws;
  unsigned short* x_bf  = (unsigned short*)p; p += (size_t)ROWS * K2 * 2;
  unsigned char*  x_f8  = (unsigned char*)p;  p += (size_t)ROWS * K2;
  unsigned char*  c_f8  = (unsigned char*)p;  p += (size_t)NCPT * K2;
  unsigned char*  cT_f8 = (unsigned char*)p;  p += (size_t)K2 * NCPT;
  unsigned short* w_bf  = (unsigned short*)p; p += (size_t)3 * 1024 * 1024 * 2;
  float* x_mag = (float*)p; p += (size_t)ROWS * 4;
  float* c_mag = (float*)p; p += (size_t)NCPT * 4;
  unsigned short* dot_bf = (unsigned short*)p; p += (size_t)ROWS * NCPT * 2;
  unsigned char*  attn_f8 = (unsigned char*)p; p += (size_t)ROWS * NCPT;
  unsigned short* h      = (unsigned short*)p; p += (size_t)ROWS * K2 * 2;
  unsigned short* ln_bf = dot_bf;  // reuse logits region after softmax

  // prep
  cast_row_mag<<<ROWS, 256, 0, stream>>>(x, x_bf, x_f8, 1.f, x_mag, K2);
  cast_row_mag<<<NCPT, 256, 0, stream>>>(cm, nullptr, c_f8, 16.f, c_mag, K2);
  transpose_f8<<<dim3(64, 64), 256, 0, stream>>>(cm, cT_f8, 2048);
  cast_w<<<1536, 256, 0, stream>>>(Wl, Wo, w_bf);

  // concept attention (fp8 MX GEMMs)
  gemm256f8<0><<<dim3(NCPT / 256, ROWS / 256), 512, 0, stream>>>(
      x_f8, c_f8, ROWS, NCPT, K2, dot_bf, x_mag, c_mag, nullptr);
  softmax_attn<<<ROWS, 256, 0, stream>>>(dot_bf, attn_f8);
  gemm256f8<1><<<dim3(K2 / 256, ROWS / 256), 512, 0, stream>>>(
      attn_f8, cT_f8, ROWS, K2, NCPT, h, nullptr, nullptr, x_bf);

  // gated FFN blocks (bf16 GEMM, fused gelu-gate + residual RMW)
  for (int l = 0; l < 2; ++l) {
    phase_ln<<<ROWS, 256, 0, stream>>>(h, gamma + l * 1024, beta + l * 1024, ln_bf);
    gemm256<2><<<dim3(DIMD / 256, 2 * ROWS / 256), 512, 0, stream>>>(
        ln_bf, w_bf + (size_t)l * 1024 * 1024, 2 * ROWS, DIMD, DIMD, h, bl + l * 1024, nullptr, nullptr);
  }

  // output projection (bf16 GEMM)
  phase_ln<<<ROWS, 256, 0, stream>>>(h, go, bto, ln_bf);
  gemm256<3><<<dim3(DIMD / 256, 2 * ROWS / 256), 512, 0, stream>>>(
      ln_bf, w_bf + 2 * 1024 * 1024, 2 * ROWS, DIMD, DIMD, out, bo, nullptr, nullptr);
}